// Round 1
// baseline (38882.895 us; speedup 1.0000x reference)
//
#include <hip/hip_runtime.h>
#include <hip/hip_bf16.h>
#include <stdint.h>

typedef __bf16 bf16;
typedef __attribute__((ext_vector_type(8))) __bf16 bf16x8;
typedef __attribute__((ext_vector_type(4))) float f32x4;

#define MFMA_B16(a,b,c) __builtin_amdgcn_mfma_f32_16x16x32_bf16((a),(b),(c),0,0,0)

// problem dims
#define BATCH  1024
#define NSTEPS 1024
#define OBS    32
#define ACTD   8
#define WIDTH  512
#define ROWS   16            // batch rows per workgroup
#define NWG    (BATCH/ROWS)  // 64
#define OUTS   ((NSTEPS+1)*OBS)

// layer-0 padded K: [y_hi(32) | y_lo(32) | act(8) | pad -> 128]
#define K0 128

// ws layout (bf16 element offsets)
#define W0P_OFF 0
#define W0P_N   (WIDTH*K0)         // 65536
#define W1_OFF  (W0P_OFF + W0P_N)
#define WBIG_N  (WIDTH*WIDTH)      // 262144
#define W2_OFF  (W1_OFF + WBIG_N)
#define W3_OFF  (W2_OFF + WBIG_N)
#define W3_N    (OBS*WIDTH)        // 16384
#define TAU_OFF (W3_OFF + W3_N)    // fp32 stored here (even offset -> 4B aligned)

__global__ void setup_kernel(const float* __restrict__ W0, const float* __restrict__ W1,
                             const float* __restrict__ W2, const float* __restrict__ W3,
                             const int* __restrict__ tau, bf16* __restrict__ wsb){
  int i = blockIdx.x*blockDim.x + threadIdx.x;
  int stride = gridDim.x*blockDim.x;
  // W0 padded+split: cols 0-31 = y_hi weights, 32-63 = same (y_lo), 64-71 = action, rest 0
  for (int idx=i; idx<W0P_N; idx+=stride){
    int r = idx >> 7, c = idx & 127;
    float v = 0.0f;
    if (c < 32)      v = W0[r*40 + c];
    else if (c < 64) v = W0[r*40 + (c-32)];
    else if (c < 72) v = W0[r*40 + 32 + (c-64)];
    wsb[W0P_OFF+idx] = (bf16)v;
  }
  for (int idx=i; idx<WBIG_N; idx+=stride) wsb[W1_OFF+idx] = (bf16)W1[idx];
  for (int idx=i; idx<WBIG_N; idx+=stride) wsb[W2_OFF+idx] = (bf16)W2[idx];
  for (int idx=i; idx<W3_N;  idx+=stride) wsb[W3_OFF+idx] = (bf16)W3[idx];
  if (i==0){
    int ti = *tau;
    float tf;
    if (ti >= -1000000 && ti <= 1000000) tf = (float)ti;     // stored as int
    else { union {int q; float f;} u; u.q = ti; tf = u.f; }  // stored as float bits
    *(float*)(wsb + TAU_OFF) = tf;
  }
}

__device__ __forceinline__ float leaky(float v){ return v < 0.0f ? 0.01f*v : v; }

// one 16x512 dense layer: hin(LDS, swizzled) @ W^T -> leaky -> hout(LDS, swizzled)
__device__ __forceinline__ void dense512(const bf16* __restrict__ hin, bf16* __restrict__ hout,
                                         const bf16* const* wb, const float* bv,
                                         int abaseH, int n0, int am, int crow0){
  f32x4 acc[4] = {{0,0,0,0},{0,0,0,0},{0,0,0,0},{0,0,0,0}};
  #pragma unroll
  for (int k=0; k<WIDTH/32; k++){
    bf16x8 a = *(const bf16x8*)&hin[abaseH ^ (k*32)];
    #pragma unroll
    for (int nt=0; nt<4; nt++){
      bf16x8 b = *(const bf16x8*)&wb[nt][k*32];
      acc[nt] = MFMA_B16(a, b, acc[nt]);
    }
  }
  #pragma unroll
  for (int nt=0; nt<4; nt++){
    int col = n0 + nt*16 + am;
    #pragma unroll
    for (int r=0; r<4; r++){
      int row = crow0 + r;
      hout[row*WIDTH + (col ^ ((row&15)<<3))] = (bf16)leaky(acc[nt][r] + bv[nt]);
    }
  }
}

__global__ __launch_bounds__(512)
void ode_kernel(const float* __restrict__ init_obs, const float* __restrict__ actions,
                const float* __restrict__ b0g, const float* __restrict__ b1g,
                const float* __restrict__ b2g, const float* __restrict__ b3g,
                const bf16* __restrict__ wsb, float* __restrict__ out){
  const bf16* w0p = wsb + W0P_OFF;
  const bf16* w1  = wsb + W1_OFF;
  const bf16* w2  = wsb + W2_OFF;
  const bf16* w3  = wsb + W3_OFF;
  const float tauf = *(const float*)(wsb + TAU_OFF);

  __shared__ alignas(16) bf16 xin[ROWS*K0];    // 4KB  layer-0 input, swizzled
  __shared__ alignas(16) bf16 hA[ROWS*WIDTH];  // 16KB swizzled
  __shared__ alignas(16) bf16 hB[ROWS*WIDTH];  // 16KB swizzled
  __shared__ float pr[4][ROWS][OBS];           // 8KB  layer-3 K-split partials
  __shared__ float yS[ROWS][OBS];              // 2KB  fp32 state

  const int t    = threadIdx.x;
  const int lane = t & 63;
  const int wave = t >> 6;          // 0..7
  const int gb0  = blockIdx.x * ROWS;
  const int am    = lane & 15;      // A-row / B-col within 16x16 tile
  const int kg    = lane >> 4;      // k-group 0..3
  const int crow0 = kg*4;           // C/D row base: row = (lane>>4)*4 + reg
  const int n0    = wave*64;        // wave's 4 n-tiles cover cols n0..n0+63

  // hoisted per-lane weight base pointers + biases (step-invariant)
  const bf16* w0b[4]; const bf16* w1b[4]; const bf16* w2b[4];
  float b0v[4], b1v[4], b2v[4];
  #pragma unroll
  for (int nt=0; nt<4; nt++){
    int col = n0 + nt*16 + am;
    w0b[nt] = w0p + (size_t)col*K0    + kg*8;
    w1b[nt] = w1  + (size_t)col*WIDTH + kg*8;
    w2b[nt] = w2  + (size_t)col*WIDTH + kg*8;
    b0v[nt] = b0g[col]; b1v[nt] = b1g[col]; b2v[nt] = b2g[col];
  }
  // layer-3: 8 waves K-split: ntb = output col-tile, kc = K-chunk of 128
  const int ntb = wave >> 2;
  const int kc  = wave & 3;
  const bf16* w3b = w3 + (size_t)(ntb*16 + am)*WIDTH + kc*128 + kg*8;

  // swizzled LDS A-fragment bases (XOR row-swizzle keeps ds_read_b128 at BW floor)
  const int swH    = (am & 15) << 3;
  const int abaseH = am*WIDTH + ((kg*8) ^ swH);
  const int abase0 = am*K0    + ((kg*8) ^ swH);

  // update-phase per-thread constants
  const int urow = t >> 5, ucol = t & 31;
  const float b3v = b3g[ucol];
  float* const outp = out + (size_t)(gb0 + urow)*OUTS + ucol;
  const int arow = (t >> 3) & 15, acol = t & 7;
  const float* const actp = actions + (size_t)(gb0 + arow)*(NSTEPS*ACTD) + acol;
  const int swU    = (urow & 15) << 3;
  const int xin_yh = urow*K0 + (ucol ^ swU);
  const int xin_yl = urow*K0 + ((ucol + 32) ^ swU);
  const int xin_ac = arow*K0 + ((64 + acol) ^ ((arow & 15) << 3));

  // ---- init: zero xin pad, load y0, emit out[:,0,:], seed xin ----
  {
    #pragma unroll
    for (int q=0; q<(ROWS*K0)/512; q++) xin[q*512 + t] = (bf16)0.0f;
    __syncthreads();
    float yv = init_obs[(gb0 + urow)*OBS + ucol];
    yS[urow][ucol] = yv;
    outp[0] = yv;
    bf16 yh = (bf16)yv;
    xin[xin_yh] = yh;
    xin[xin_yl] = (bf16)(yv - (float)yh);
    if (t < 128) xin[xin_ac] = (bf16)actp[0];
  }
  __syncthreads();

  for (int s=0; s<NSTEPS; ++s){
    // ---- layer 0: xin(16xK0) @ W0p^T -> hA ----
    {
      f32x4 acc[4] = {{0,0,0,0},{0,0,0,0},{0,0,0,0},{0,0,0,0}};
      #pragma unroll
      for (int k=0; k<K0/32; k++){
        bf16x8 a = *(const bf16x8*)&xin[abase0 ^ (k*32)];
        #pragma unroll
        for (int nt=0; nt<4; nt++){
          bf16x8 b = *(const bf16x8*)&w0b[nt][k*32];
          acc[nt] = MFMA_B16(a, b, acc[nt]);
        }
      }
      #pragma unroll
      for (int nt=0; nt<4; nt++){
        int col = n0 + nt*16 + am;
        #pragma unroll
        for (int r=0; r<4; r++){
          int row = crow0 + r;
          hA[row*WIDTH + (col ^ ((row&15)<<3))] = (bf16)leaky(acc[nt][r] + b0v[nt]);
        }
      }
    }
    __syncthreads();

    dense512(hA, hB, w1b, b1v, abaseH, n0, am, crow0);   // layer 1
    __syncthreads();
    dense512(hB, hA, w2b, b2v, abaseH, n0, am, crow0);   // layer 2
    __syncthreads();

    // ---- layer 3 (16x32, K=512 split 4-ways across waves) ----
    {
      f32x4 acc = {0,0,0,0};
      #pragma unroll
      for (int kk=0; kk<4; kk++){
        int k = kc*4 + kk;
        bf16x8 a = *(const bf16x8*)&hA[abaseH ^ (k*32)];
        bf16x8 b = *(const bf16x8*)&w3b[kk*32];
        acc = MFMA_B16(a, b, acc);
      }
      #pragma unroll
      for (int r=0; r<4; r++) pr[kc][crow0 + r][ntb*16 + am] = acc[r];
    }
    __syncthreads();

    // ---- update: reduce partials, Euler step, emit, reseed xin ----
    {
      float dy = pr[0][urow][ucol] + pr[1][urow][ucol]
               + pr[2][urow][ucol] + pr[3][urow][ucol] + b3v;
      float yn = yS[urow][ucol] + tauf * dy;
      yS[urow][ucol] = yn;
      outp[(size_t)(s+1)*OBS] = yn;
      bf16 yh = (bf16)yn;
      xin[xin_yh] = yh;
      xin[xin_yl] = (bf16)(yn - (float)yh);
      if (t < 128 && s+1 < NSTEPS) xin[xin_ac] = (bf16)actp[(size_t)(s+1)*ACTD];
    }
    __syncthreads();
  }
}

extern "C" void kernel_launch(void* const* d_in, const int* in_sizes, int n_in,
                              void* d_out, int out_size, void* d_ws, size_t ws_size,
                              hipStream_t stream){
  const float* init_obs = (const float*)d_in[0];
  const float* actions  = (const float*)d_in[1];
  const float* W0 = (const float*)d_in[2];
  const float* b0 = (const float*)d_in[3];
  const float* W1 = (const float*)d_in[4];
  const float* b1 = (const float*)d_in[5];
  const float* W2 = (const float*)d_in[6];
  const float* b2 = (const float*)d_in[7];
  const float* W3 = (const float*)d_in[8];
  const float* b3 = (const float*)d_in[9];
  const int*  tau = (const int*)d_in[10];
  bf16* wsb = (bf16*)d_ws;
  float* out = (float*)d_out;

  hipLaunchKernelGGL(setup_kernel, dim3(512), dim3(256), 0, stream,
                     W0, W1, W2, W3, tau, wsb);
  hipLaunchKernelGGL(ode_kernel, dim3(NWG), dim3(512), 0, stream,
                     init_obs, actions, b0, b1, b2, b3, (const bf16*)wsb, out);
}